// Round 7
// baseline (570.054 us; speedup 1.0000x reference)
//
#include <hip/hip_runtime.h>
#include <math.h>

// DigitCaps routing constants
#define B_SZ 64
#define P_SZ 2048
#define PD   16
#define N_SZ 32
#define D_SZ 32
#define ND   1024            // N_SZ * D_SZ
#define PC   8               // p per fused block (pass0)
#define BC   8               // b per fused block (pass0)
#define NPC  (P_SZ / PC)     // 256
#define NBC  (B_SZ / BC)     // 8
#define PP   16              // p per wave in routing_wave
#define NPCH (P_SZ / PP)     // 128 partials

typedef _Float16 half2_t __attribute__((ext_vector_type(2)));
typedef unsigned u32x4 __attribute__((ext_vector_type(4)));
typedef unsigned u32x2 __attribute__((ext_vector_type(2)));

__device__ __forceinline__ float dot2acc(unsigned a, unsigned b, float acc) {
#if __has_builtin(__builtin_amdgcn_fdot2)
    return __builtin_amdgcn_fdot2(__builtin_bit_cast(half2_t, a),
                                  __builtin_bit_cast(half2_t, b), acc, false);
#else
    const half2_t ha = __builtin_bit_cast(half2_t, a);
    const half2_t hb = __builtin_bit_cast(half2_t, b);
    return acc + (float)ha[0] * (float)hb[0] + (float)ha[1] * (float)hb[1];
#endif
}

__device__ __forceinline__ unsigned packh2(float a, float b) {
    half2_t h; h[0] = (_Float16)a; h[1] = (_Float16)b;
    return __builtin_bit_cast(unsigned, h);
}

__device__ __forceinline__ float4 unpackh4(uint2 u) {
    const half2_t lo = __builtin_bit_cast(half2_t, u.x);
    const half2_t hi = __builtin_bit_cast(half2_t, u.y);
    return make_float4((float)lo[0], (float)lo[1], (float)hi[0], (float)hi[1]);
}

__device__ __forceinline__ float dot4(const float4 a, const float4 b) {
    return a.x * b.x + a.y * b.y + a.z * b.z + a.w * b.w;
}

// non-temporal helpers: stream hints for read-once / write-once data
__device__ __forceinline__ uint4 ntload4(const uint4* p) {
    const u32x4 v = __builtin_nontemporal_load((const u32x4*)p);
    uint4 r; r.x = v[0]; r.y = v[1]; r.z = v[2]; r.w = v[3];
    return r;
}
__device__ __forceinline__ void ntstore2(uint2* p, uint2 x) {
    u32x2 v; v[0] = x.x; v[1] = x.y;
    __builtin_nontemporal_store(v, (u32x2*)p);
}

// r14 merged repack: blocks [0,8192) repack W, [8192,9216) repack x.
// W part (r12 mapping): reads 64 B dense/thread, writes 2 coalesced uint4.
// w2u4[(p*8+k)*256 + t] holds w[p][4t + (k>>1)][(k&1)*8 .. +7] as f16.
__global__ __launch_bounds__(256) void repack_wx(
    const float4* __restrict__ w4, uint4* __restrict__ w2u4,
    const float4* __restrict__ x4, uint4* __restrict__ x2)
{
    const int blk = blockIdx.x;
    if (blk < 8192) {
        const size_t g = (size_t)blk * 256 + threadIdx.x;  // < 2097152
        const int p    = (int)(g >> 10);
        const int q    = (int)((g >> 8) & 3);
        const int t    = (int)(g & 255);
        const size_t f0 = ((size_t)p * 1024 + 4 * t + q) * 4;
        const float4 a = w4[f0], b = w4[f0 + 1], c = w4[f0 + 2], d = w4[f0 + 3];
        uint4 o0, o1;
        o0.x = packh2(a.x, a.y); o0.y = packh2(a.z, a.w);
        o0.z = packh2(b.x, b.y); o0.w = packh2(b.z, b.w);
        o1.x = packh2(c.x, c.y); o1.y = packh2(c.z, c.w);
        o1.z = packh2(d.x, d.y); o1.w = packh2(d.z, d.w);
        w2u4[((size_t)p * 8 + 2 * q) * 256 + t]     = o0;
        w2u4[((size_t)p * 8 + 2 * q + 1) * 256 + t] = o1;
    } else {
        const size_t g = (size_t)(blk - 8192) * 256 + threadIdx.x;  // < 262144
        const float4 a = x4[g * 2], b = x4[g * 2 + 1];
        uint4 o;
        o.x = packh2(a.x, a.y); o.y = packh2(a.z, a.w);
        o.z = packh2(b.x, b.y); o.w = packh2(b.z, b.w);
        x2[g] = o;
    }
}

__device__ __forceinline__ float4 predict(const uint4 (&W)[8], const unsigned* X) {
    float s; float4 pr;
    s = dot2acc(W[0].x, X[0], 0.f); s = dot2acc(W[0].y, X[1], s);
    s = dot2acc(W[0].z, X[2], s);   s = dot2acc(W[0].w, X[3], s);
    s = dot2acc(W[1].x, X[4], s);   s = dot2acc(W[1].y, X[5], s);
    s = dot2acc(W[1].z, X[6], s);   s = dot2acc(W[1].w, X[7], s);
    pr.x = s;
    s = dot2acc(W[2].x, X[0], 0.f); s = dot2acc(W[2].y, X[1], s);
    s = dot2acc(W[2].z, X[2], s);   s = dot2acc(W[2].w, X[3], s);
    s = dot2acc(W[3].x, X[4], s);   s = dot2acc(W[3].y, X[5], s);
    s = dot2acc(W[3].z, X[6], s);   s = dot2acc(W[3].w, X[7], s);
    pr.y = s;
    s = dot2acc(W[4].x, X[0], 0.f); s = dot2acc(W[4].y, X[1], s);
    s = dot2acc(W[4].z, X[2], s);   s = dot2acc(W[4].w, X[3], s);
    s = dot2acc(W[5].x, X[4], s);   s = dot2acc(W[5].y, X[5], s);
    s = dot2acc(W[5].z, X[6], s);   s = dot2acc(W[5].w, X[7], s);
    pr.z = s;
    s = dot2acc(W[6].x, X[0], 0.f); s = dot2acc(W[6].y, X[1], s);
    s = dot2acc(W[6].z, X[2], s);   s = dot2acc(W[6].w, X[3], s);
    s = dot2acc(W[7].x, X[4], s);   s = dot2acc(W[7].y, X[5], s);
    s = dot2acc(W[7].z, X[6], s);   s = dot2acc(W[7].w, X[7], s);
    pr.w = s;
    return pr;
}

// r12 fused kernel: 1D grid of 2048 blocks, XCD-sliced W ownership (verified
// r12: FETCH 266 -> 37 MB). r15: pred stores are non-temporal (268 MB
// write-once stream should not allocate in L2).
// Thread t owns nd = 4t..4t+3 (n = t>>3).
// MODE==0: c=1/32; MODE==1: b=agr; MODE==2: b+=agr; c=softmax_n(b)
template <int MODE, bool STORE_PRED>
__global__ __launch_bounds__(256, 4) void fused_pass(
    const uint4* __restrict__ x2, const uint4* __restrict__ w2,
    const float* __restrict__ v_in, float* __restrict__ b_io,
    uint2* __restrict__ s_part, uint2* __restrict__ pred_out)
{
    const int t     = threadIdx.x;
    const int gblk  = blockIdx.x;          // 0..2047
    const int xcd   = gblk & 7;
    const int j     = gblk >> 3;           // 0..255
    const int pc    = xcd * (NPC / 8) + (j >> 3);
    const int bc    = j & 7;
    const int p0    = pc * PC, b0 = bc * BC;
    const int n     = t >> 3;
    const int wv    = t >> 6;
    const int lane  = t & 63;

    __shared__ uint2 vs2[BC * 256];        // v as f16 pairs, 16 KiB
    __shared__ float sden[2][16];

    if (MODE != 0) {
        const float4* vg = (const float4*)v_in;
        #pragma unroll
        for (int i = 0; i < BC; ++i) {
            const int idx = t + 256 * i;
            const float4 vv = vg[(size_t)(b0 + (idx >> 8)) * 256 + (idx & 255)];
            uint2 u = { packh2(vv.x, vv.y), packh2(vv.z, vv.w) };
            vs2[idx] = u;
        }
        __syncthreads();
    }

    float4 sacc[BC];
    #pragma unroll
    for (int i = 0; i < BC; ++i) sacc[i] = make_float4(0.f, 0.f, 0.f, 0.f);

    const uint4* wbase = w2 + (size_t)p0 * (8 * 256) + t;
    const uint4* xbase = x2 + (size_t)b0 * P_SZ * 2;

    for (int pl = 0; pl < PC; ++pl) {
        const int p = p0 + pl;
        uint4 W[8];
        #pragma unroll
        for (int k = 0; k < 8; ++k) W[k] = wbase[(size_t)pl * 2048 + k * 256];

        if (MODE == 0) {
            #pragma unroll
            for (int j2 = 0; j2 < BC; ++j2) {
                const uint4* xp = xbase + ((size_t)j2 * P_SZ + p) * 2;
                const uint4 xa = xp[0], xb = xp[1];
                const unsigned X[8] = {xa.x, xa.y, xa.z, xa.w, xb.x, xb.y, xb.z, xb.w};
                const float4 pr = predict(W, X);
                if (STORE_PRED) {
                    uint2 u = { packh2(pr.x, pr.y), packh2(pr.z, pr.w) };
                    ntstore2(&pred_out[((size_t)(b0 + j2) * P_SZ + p) * 256 + t], u);
                }
                sacc[j2].x += pr.x * (1.0f / 32.0f);
                sacc[j2].y += pr.y * (1.0f / 32.0f);
                sacc[j2].z += pr.z * (1.0f / 32.0f);
                sacc[j2].w += pr.w * (1.0f / 32.0f);
            }
        } else {
            #pragma unroll
            for (int h = 0; h < 2; ++h) {
                const int par = h;
                float4 pr[4];
                float  ap[4], ee[4], bold[4];
                if (MODE == 2) {
                    #pragma unroll
                    for (int j2 = 0; j2 < 4; ++j2)
                        bold[j2] = b_io[((size_t)(b0 + h * 4 + j2) * P_SZ + p) * N_SZ + n];
                }
                #pragma unroll
                for (int j2 = 0; j2 < 4; ++j2) {
                    const int bl = h * 4 + j2;
                    const uint4* xp = xbase + ((size_t)bl * P_SZ + p) * 2;
                    const uint4 xa = xp[0], xb = xp[1];
                    const unsigned X[8] = {xa.x, xa.y, xa.z, xa.w, xb.x, xb.y, xb.z, xb.w};
                    pr[j2] = predict(W, X);
                    ap[j2] = dot4(pr[j2], unpackh4(vs2[bl * 256 + t]));
                }
                #pragma unroll
                for (int j2 = 0; j2 < 4; ++j2) {
                    ap[j2] += __shfl_xor(ap[j2], 1);
                    ap[j2] += __shfl_xor(ap[j2], 2);
                    ap[j2] += __shfl_xor(ap[j2], 4);
                }
                #pragma unroll
                for (int j2 = 0; j2 < 4; ++j2) {
                    const size_t bidx = ((size_t)(b0 + h * 4 + j2) * P_SZ + p) * N_SZ + n;
                    const float bnew = (MODE == 1) ? ap[j2] : (bold[j2] + ap[j2]);
                    if ((t & 7) == 0) b_io[bidx] = bnew;
                    ee[j2] = __expf(bnew);
                }
                #pragma unroll
                for (int j2 = 0; j2 < 4; ++j2) {
                    float ps = ee[j2];
                    ps += __shfl_xor(ps, 8);
                    ps += __shfl_xor(ps, 16);
                    ps += __shfl_xor(ps, 32);
                    ap[j2] = ps;
                }
                if (lane == 0) {
                    #pragma unroll
                    for (int j2 = 0; j2 < 4; ++j2) sden[par][j2 * 4 + wv] = ap[j2];
                }
                __syncthreads();  // parity-buffered sden: race-free (r2 argument)
                #pragma unroll
                for (int j2 = 0; j2 < 4; ++j2) {
                    const int bl = h * 4 + j2;
                    const float4 dd = *(const float4*)&sden[par][j2 * 4];
                    const float c = ee[j2] * __builtin_amdgcn_rcpf(dd.x + dd.y + dd.z + dd.w);
                    sacc[bl].x += c * pr[j2].x; sacc[bl].y += c * pr[j2].y;
                    sacc[bl].z += c * pr[j2].z; sacc[bl].w += c * pr[j2].w;
                }
            }
        }
    }

    #pragma unroll
    for (int j2 = 0; j2 < BC; ++j2) {
        uint2 u = { packh2(sacc[j2].x, sacc[j2].y), packh2(sacc[j2].z, sacc[j2].w) };
        s_part[((size_t)pc * B_SZ + (b0 + j2)) * 256 + t] = u;
    }
}

// -------- r15 routing: r13 contiguous mapping + nt loads + prefetch --------
// One wave owns (b, 16-p chunk). Lane l owns nd [8l,8l+8) (n_lo=l>>2,
// d-quarter l&3) and nd [512+8l,+8) (n_hi=16+(l>>2)). XCD-aware decode:
// xcd = bid&7 owns b range [xcd*8, xcd*8+8) -> each XCD streams a contiguous
// 32 MB pred slice. Cumulative-v logits: b_k = pred . vsum.
// Software-pipelined: next iteration's 2 uint4 loads issued before compute.
__global__ __launch_bounds__(256, 8) void routing_wave(
    const uint4* __restrict__ pred, const float* __restrict__ vsum,
    uint4* __restrict__ s_part)
{
    const int t    = threadIdx.x;
    const int wv   = t >> 6;
    const int lane = t & 63;
    const int xcd  = blockIdx.x & 7;
    const int jj   = blockIdx.x >> 3;         // 0..255
    const int gl   = jj * 4 + wv;             // 0..1023 within XCD
    const int b    = xcd * 8 + (gl >> 7);     // 0..63
    const int pch  = gl & (NPCH - 1);         // 0..127
    const int p0   = pch * PP;

    // vsum (f32) -> f16 pairs in regs: 8 d-values for (b,n_lo) and (b,n_hi)
    unsigned vlo[4], vhi[4];
    {
        const float4* vp = (const float4*)vsum + ((size_t)b * 256 + 2 * lane);
        const float4 a0 = vp[0],   a1 = vp[1];
        const float4 b0 = vp[128], b1 = vp[129];
        vlo[0] = packh2(a0.x, a0.y); vlo[1] = packh2(a0.z, a0.w);
        vlo[2] = packh2(a1.x, a1.y); vlo[3] = packh2(a1.z, a1.w);
        vhi[0] = packh2(b0.x, b0.y); vhi[1] = packh2(b0.z, b0.w);
        vhi[2] = packh2(b1.x, b1.y); vhi[3] = packh2(b1.z, b1.w);
    }

    float slo[8], shi[8];
    #pragma unroll
    for (int i = 0; i < 8; ++i) { slo[i] = 0.f; shi[i] = 0.f; }

    const uint4* pb = pred + ((size_t)b * P_SZ + p0) * 128 + lane;

    uint4 A  = ntload4(pb);        // nd [8*lane, +8)      contiguous 1 KiB
    uint4 Bq = ntload4(pb + 64);   // nd [512+8*lane, +8)  contiguous 1 KiB

    #pragma unroll
    for (int pl = 0; pl < PP; ++pl) {
        uint4 An, Bn;
        if (pl + 1 < PP) {
            An = ntload4(pb + 128);
            Bn = ntload4(pb + 192);
        }
        float alo = 0.f, ahi = 0.f;
        alo = dot2acc(A.x,  vlo[0], alo); alo = dot2acc(A.y,  vlo[1], alo);
        alo = dot2acc(A.z,  vlo[2], alo); alo = dot2acc(A.w,  vlo[3], alo);
        ahi = dot2acc(Bq.x, vhi[0], ahi); ahi = dot2acc(Bq.y, vhi[1], ahi);
        ahi = dot2acc(Bq.z, vhi[2], ahi); ahi = dot2acc(Bq.w, vhi[3], ahi);
        alo += __shfl_xor(alo, 1);  alo += __shfl_xor(alo, 2);
        ahi += __shfl_xor(ahi, 1);  ahi += __shfl_xor(ahi, 2);
        const float elo = __expf(alo), ehi = __expf(ahi);
        float den = elo + ehi;
        den += __shfl_xor(den, 4);   den += __shfl_xor(den, 8);
        den += __shfl_xor(den, 16);  den += __shfl_xor(den, 32);
        const float r   = __builtin_amdgcn_rcpf(den);
        const float clo = elo * r, chi = ehi * r;
        const unsigned XA[4] = {A.x,  A.y,  A.z,  A.w};
        const unsigned XB[4] = {Bq.x, Bq.y, Bq.z, Bq.w};
        #pragma unroll
        for (int i = 0; i < 4; ++i) {
            const half2_t ha = __builtin_bit_cast(half2_t, XA[i]);
            const half2_t hb = __builtin_bit_cast(half2_t, XB[i]);
            slo[2 * i]     += clo * (float)ha[0];
            slo[2 * i + 1] += clo * (float)ha[1];
            shi[2 * i]     += chi * (float)hb[0];
            shi[2 * i + 1] += chi * (float)hb[1];
        }
        A = An; Bq = Bn;
        pb += 128;
    }

    uint4 o0, o1;
    o0.x = packh2(slo[0], slo[1]); o0.y = packh2(slo[2], slo[3]);
    o0.z = packh2(slo[4], slo[5]); o0.w = packh2(slo[6], slo[7]);
    o1.x = packh2(shi[0], shi[1]); o1.y = packh2(shi[2], shi[3]);
    o1.z = packh2(shi[4], shi[5]); o1.w = packh2(shi[6], shi[7]);
    uint4* sp = s_part + ((size_t)pch * B_SZ + b) * 128;
    sp[lane]      = o0;   // nd [8*lane, +8)      contiguous
    sp[64 + lane] = o1;   // nd [512+8*lane, +8)  contiguous
}

// s[b][nd] = sum over NPCH wave-partials (f16, fp32 accum); v = squash(s).
// VMODE 1: dst += v (vsum accumulate); VMODE 2: dst = v (out)
template <int VMODE>
__global__ __launch_bounds__(256) void reduce_squash2(
    const uint2* __restrict__ s_part, float* __restrict__ dst)
{
    const int t   = threadIdx.x;
    const int b   = blockIdx.x;
    const int q   = blockIdx.y;
    const int l   = t & 63;
    const int sub = t >> 6;
    const int nd4 = q * 64 + l;

    float4 s = make_float4(0.f, 0.f, 0.f, 0.f);
    for (int i = 0; i < NPCH / 4; ++i) {
        const int pcid = sub + 4 * i;
        const float4 v = unpackh4(s_part[((size_t)pcid * B_SZ + b) * 256 + nd4]);
        s.x += v.x; s.y += v.y; s.z += v.z; s.w += v.w;
    }
    __shared__ float4 red[3][64];
    if (sub > 0) red[sub - 1][l] = s;
    __syncthreads();
    if (t < 64) {
        #pragma unroll
        for (int wvi = 0; wvi < 3; ++wvi) {
            const float4 r = red[wvi][t];
            s.x += r.x; s.y += r.y; s.z += r.z; s.w += r.w;
        }
        float sq = dot4(s, s);
        sq += __shfl_xor(sq, 1);
        sq += __shfl_xor(sq, 2);
        sq += __shfl_xor(sq, 4);
        const float f = sq / ((1.0f + sq) * sqrtf(sq + 1e-7f));
        float4 o = make_float4(f * s.x, f * s.y, f * s.z, f * s.w);
        if (VMODE == 1) {
            const float4 old = ((const float4*)dst)[(size_t)b * 256 + nd4];
            o.x += old.x; o.y += old.y; o.z += old.z; o.w += old.w;
        }
        ((float4*)dst)[(size_t)b * 256 + nd4] = o;
    }
}

// old reducer (NPC=256 partials) — consumes pass0's s_part
__global__ __launch_bounds__(256) void reduce_squash(
    const uint2* __restrict__ s_part, float* __restrict__ dst)
{
    const int t  = threadIdx.x;
    const int b  = blockIdx.x;
    const int q  = blockIdx.y;
    const int l  = t & 63;
    const int sub = t >> 6;
    const int nd4 = q * 64 + l;

    float4 s = make_float4(0.f, 0.f, 0.f, 0.f);
    for (int i = 0; i < NPC / 4; ++i) {
        const int pcid = sub + 4 * i;
        const float4 v = unpackh4(s_part[((size_t)pcid * B_SZ + b) * 256 + nd4]);
        s.x += v.x; s.y += v.y; s.z += v.z; s.w += v.w;
    }
    __shared__ float4 red[3][64];
    if (sub > 0) red[sub - 1][l] = s;
    __syncthreads();
    if (t < 64) {
        #pragma unroll
        for (int wvi = 0; wvi < 3; ++wvi) {
            const float4 r = red[wvi][t];
            s.x += r.x; s.y += r.y; s.z += r.z; s.w += r.w;
        }
        float sq = dot4(s, s);
        sq += __shfl_xor(sq, 1);
        sq += __shfl_xor(sq, 2);
        sq += __shfl_xor(sq, 4);
        const float f = sq / ((1.0f + sq) * sqrtf(sq + 1e-7f));
        ((float4*)dst)[(size_t)b * 256 + nd4] =
            make_float4(f * s.x, f * s.y, f * s.z, f * s.w);
    }
}

extern "C" void kernel_launch(void* const* d_in, const int* in_sizes, int n_in,
                              void* d_out, int out_size, void* d_ws, size_t ws_size,
                              hipStream_t stream)
{
    const float* x = (const float*)d_in[0];   // (B,P,pD)
    const float* w = (const float*)d_in[1];   // (P,N,D,pD)
    float* out = (float*)d_out;               // (B,N,D)
    float* ws  = (float*)d_ws;

    // ---- workspace layout (float offsets):
    //   vsum  : [0,        65536)      256 KiB
    //   s_part: [65536,    8454144)    32 MiB pass0 layout; routing's 16 MiB
    //           aliases the front (sequenced: pass0 partials consumed first)
    //   w2    : [8454144,  25231360)   64 MiB
    //   x2    : [25231360, 26279936)    4 MiB
    //   pred  : [26279936, 93388800)  256 MiB
    float*    v_buf  = ws;
    uint2*    s_part = (uint2*)(ws + 65536);
    unsigned* w2     = (unsigned*)(ws + 8454144);
    uint4*    x2     = (uint4*)(ws + 25231360);
    uint2*    pred   = (uint2*)(ws + 26279936);
    float*    b_fb   = ws + 26279936;             // fallback only (pred unused)
    const size_t need = 93388800ull * 4ull;       // 373,555,200 B

    repack_wx<<<dim3(9216), dim3(256), 0, stream>>>((const float4*)w, (uint4*)w2,
                                                    (const float4*)x, (uint4*)x2);

    dim3 fg(NPC * NBC), fb(256);   // r12: 1D grid, XCD-sliced decode in-kernel
    dim3 rg(B_SZ, 4), rb(256);

    if (ws_size >= need) {
        // pass0 computes pred once + stores f16 (nt); routing passes stream
        // pred (nt loads) with cumulative-v logits.
        fused_pass<0, true><<<fg, fb, 0, stream>>>(x2, (const uint4*)w2, nullptr,
                                                   nullptr, s_part, pred);
        reduce_squash<<<rg, rb, 0, stream>>>(s_part, v_buf);          // vsum = v1

        routing_wave<<<dim3(2048), dim3(256), 0, stream>>>(
            (const uint4*)pred, v_buf, (uint4*)s_part);
        reduce_squash2<1><<<rg, rb, 0, stream>>>(s_part, v_buf);      // vsum += v2

        routing_wave<<<dim3(2048), dim3(256), 0, stream>>>(
            (const uint4*)pred, v_buf, (uint4*)s_part);
        reduce_squash2<1><<<rg, rb, 0, stream>>>(s_part, v_buf);      // vsum += v3

        routing_wave<<<dim3(2048), dim3(256), 0, stream>>>(
            (const uint4*)pred, v_buf, (uint4*)s_part);
        reduce_squash2<2><<<rg, rb, 0, stream>>>(s_part, out);        // final v
    } else {
        // r7 fallback (recompute pred every pass)
        fused_pass<0, false><<<fg, fb, 0, stream>>>(x2, (const uint4*)w2, nullptr,
                                                    nullptr, s_part, nullptr);
        reduce_squash<<<rg, rb, 0, stream>>>(s_part, v_buf);
        fused_pass<1, false><<<fg, fb, 0, stream>>>(x2, (const uint4*)w2, v_buf,
                                                    b_fb, s_part, nullptr);
        reduce_squash<<<rg, rb, 0, stream>>>(s_part, v_buf);
        fused_pass<2, false><<<fg, fb, 0, stream>>>(x2, (const uint4*)w2, v_buf,
                                                    b_fb, s_part, nullptr);
        reduce_squash<<<rg, rb, 0, stream>>>(s_part, v_buf);
        fused_pass<2, false><<<fg, fb, 0, stream>>>(x2, (const uint4*)w2, v_buf,
                                                    b_fb, s_part, nullptr);
        reduce_squash<<<rg, rb, 0, stream>>>(s_part, out);
    }
}

// Round 9
// 431.142 us; speedup vs baseline: 1.3222x; 1.3222x over previous
//
#include <hip/hip_runtime.h>
#include <math.h>

// DigitCaps routing constants
#define B_SZ 64
#define P_SZ 2048
#define PD   16
#define N_SZ 32
#define D_SZ 32
#define ND   1024            // N_SZ * D_SZ
#define PC   8               // p per fused block (pass0)
#define BC   8               // b per fused block (pass0)
#define NPC  (P_SZ / PC)     // 256
#define NBC  (B_SZ / BC)     // 8
#define PP   16              // p per wave in routing_wave
#define NPCH (P_SZ / PP)     // 128 partials

typedef _Float16 half2_t __attribute__((ext_vector_type(2)));
typedef unsigned u32x4 __attribute__((ext_vector_type(4)));
typedef unsigned u32x2 __attribute__((ext_vector_type(2)));

__device__ __forceinline__ float dot2acc(unsigned a, unsigned b, float acc) {
#if __has_builtin(__builtin_amdgcn_fdot2)
    return __builtin_amdgcn_fdot2(__builtin_bit_cast(half2_t, a),
                                  __builtin_bit_cast(half2_t, b), acc, false);
#else
    const half2_t ha = __builtin_bit_cast(half2_t, a);
    const half2_t hb = __builtin_bit_cast(half2_t, b);
    return acc + (float)ha[0] * (float)hb[0] + (float)ha[1] * (float)hb[1];
#endif
}

__device__ __forceinline__ unsigned packh2(float a, float b) {
    half2_t h; h[0] = (_Float16)a; h[1] = (_Float16)b;
    return __builtin_bit_cast(unsigned, h);
}

__device__ __forceinline__ float4 unpackh4(uint2 u) {
    const half2_t lo = __builtin_bit_cast(half2_t, u.x);
    const half2_t hi = __builtin_bit_cast(half2_t, u.y);
    return make_float4((float)lo[0], (float)lo[1], (float)hi[0], (float)hi[1]);
}

__device__ __forceinline__ float dot4(const float4 a, const float4 b) {
    return a.x * b.x + a.y * b.y + a.z * b.z + a.w * b.w;
}

// non-temporal helpers: stream hints for read-once / write-once data
__device__ __forceinline__ uint4 ntload4(const uint4* p) {
    const u32x4 v = __builtin_nontemporal_load((const u32x4*)p);
    uint4 r; r.x = v[0]; r.y = v[1]; r.z = v[2]; r.w = v[3];
    return r;
}
__device__ __forceinline__ void ntstore2(uint2* p, uint2 x) {
    u32x2 v; v[0] = x.x; v[1] = x.y;
    __builtin_nontemporal_store(v, (u32x2*)p);
}

// r14 merged repack: blocks [0,8192) repack W, [8192,9216) repack x.
// W part (r12 mapping): reads 64 B dense/thread, writes 2 coalesced uint4.
// w2u4[(p*8+k)*256 + t] holds w[p][4t + (k>>1)][(k&1)*8 .. +7] as f16.
__global__ __launch_bounds__(256) void repack_wx(
    const float4* __restrict__ w4, uint4* __restrict__ w2u4,
    const float4* __restrict__ x4, uint4* __restrict__ x2)
{
    const int blk = blockIdx.x;
    if (blk < 8192) {
        const size_t g = (size_t)blk * 256 + threadIdx.x;  // < 2097152
        const int p    = (int)(g >> 10);
        const int q    = (int)((g >> 8) & 3);
        const int t    = (int)(g & 255);
        const size_t f0 = ((size_t)p * 1024 + 4 * t + q) * 4;
        const float4 a = w4[f0], b = w4[f0 + 1], c = w4[f0 + 2], d = w4[f0 + 3];
        uint4 o0, o1;
        o0.x = packh2(a.x, a.y); o0.y = packh2(a.z, a.w);
        o0.z = packh2(b.x, b.y); o0.w = packh2(b.z, b.w);
        o1.x = packh2(c.x, c.y); o1.y = packh2(c.z, c.w);
        o1.z = packh2(d.x, d.y); o1.w = packh2(d.z, d.w);
        w2u4[((size_t)p * 8 + 2 * q) * 256 + t]     = o0;
        w2u4[((size_t)p * 8 + 2 * q + 1) * 256 + t] = o1;
    } else {
        const size_t g = (size_t)(blk - 8192) * 256 + threadIdx.x;  // < 262144
        const float4 a = x4[g * 2], b = x4[g * 2 + 1];
        uint4 o;
        o.x = packh2(a.x, a.y); o.y = packh2(a.z, a.w);
        o.z = packh2(b.x, b.y); o.w = packh2(b.z, b.w);
        x2[g] = o;
    }
}

__device__ __forceinline__ float4 predict(const uint4 (&W)[8], const unsigned* X) {
    float s; float4 pr;
    s = dot2acc(W[0].x, X[0], 0.f); s = dot2acc(W[0].y, X[1], s);
    s = dot2acc(W[0].z, X[2], s);   s = dot2acc(W[0].w, X[3], s);
    s = dot2acc(W[1].x, X[4], s);   s = dot2acc(W[1].y, X[5], s);
    s = dot2acc(W[1].z, X[6], s);   s = dot2acc(W[1].w, X[7], s);
    pr.x = s;
    s = dot2acc(W[2].x, X[0], 0.f); s = dot2acc(W[2].y, X[1], s);
    s = dot2acc(W[2].z, X[2], s);   s = dot2acc(W[2].w, X[3], s);
    s = dot2acc(W[3].x, X[4], s);   s = dot2acc(W[3].y, X[5], s);
    s = dot2acc(W[3].z, X[6], s);   s = dot2acc(W[3].w, X[7], s);
    pr.y = s;
    s = dot2acc(W[4].x, X[0], 0.f); s = dot2acc(W[4].y, X[1], s);
    s = dot2acc(W[4].z, X[2], s);   s = dot2acc(W[4].w, X[3], s);
    s = dot2acc(W[5].x, X[4], s);   s = dot2acc(W[5].y, X[5], s);
    s = dot2acc(W[5].z, X[6], s);   s = dot2acc(W[5].w, X[7], s);
    pr.z = s;
    s = dot2acc(W[6].x, X[0], 0.f); s = dot2acc(W[6].y, X[1], s);
    s = dot2acc(W[6].z, X[2], s);   s = dot2acc(W[6].w, X[3], s);
    s = dot2acc(W[7].x, X[4], s);   s = dot2acc(W[7].y, X[5], s);
    s = dot2acc(W[7].z, X[6], s);   s = dot2acc(W[7].w, X[7], s);
    pr.w = s;
    return pr;
}

// r12 fused kernel: 1D grid of 2048 blocks, XCD-sliced W ownership (verified
// r12: FETCH 266 -> 37 MB). r15: pred stores non-temporal.
// Thread t owns nd = 4t..4t+3 (n = t>>3).
// MODE==0: c=1/32; MODE==1: b=agr; MODE==2: b+=agr; c=softmax_n(b)
template <int MODE, bool STORE_PRED>
__global__ __launch_bounds__(256, 4) void fused_pass(
    const uint4* __restrict__ x2, const uint4* __restrict__ w2,
    const float* __restrict__ v_in, float* __restrict__ b_io,
    uint2* __restrict__ s_part, uint2* __restrict__ pred_out)
{
    const int t     = threadIdx.x;
    const int gblk  = blockIdx.x;          // 0..2047
    const int xcd   = gblk & 7;
    const int j     = gblk >> 3;           // 0..255
    const int pc    = xcd * (NPC / 8) + (j >> 3);
    const int bc    = j & 7;
    const int p0    = pc * PC, b0 = bc * BC;
    const int n     = t >> 3;
    const int wv    = t >> 6;
    const int lane  = t & 63;

    __shared__ uint2 vs2[BC * 256];        // v as f16 pairs, 16 KiB
    __shared__ float sden[2][16];

    if (MODE != 0) {
        const float4* vg = (const float4*)v_in;
        #pragma unroll
        for (int i = 0; i < BC; ++i) {
            const int idx = t + 256 * i;
            const float4 vv = vg[(size_t)(b0 + (idx >> 8)) * 256 + (idx & 255)];
            uint2 u = { packh2(vv.x, vv.y), packh2(vv.z, vv.w) };
            vs2[idx] = u;
        }
        __syncthreads();
    }

    float4 sacc[BC];
    #pragma unroll
    for (int i = 0; i < BC; ++i) sacc[i] = make_float4(0.f, 0.f, 0.f, 0.f);

    const uint4* wbase = w2 + (size_t)p0 * (8 * 256) + t;
    const uint4* xbase = x2 + (size_t)b0 * P_SZ * 2;

    for (int pl = 0; pl < PC; ++pl) {
        const int p = p0 + pl;
        uint4 W[8];
        #pragma unroll
        for (int k = 0; k < 8; ++k) W[k] = wbase[(size_t)pl * 2048 + k * 256];

        if (MODE == 0) {
            #pragma unroll
            for (int j2 = 0; j2 < BC; ++j2) {
                const uint4* xp = xbase + ((size_t)j2 * P_SZ + p) * 2;
                const uint4 xa = xp[0], xb = xp[1];
                const unsigned X[8] = {xa.x, xa.y, xa.z, xa.w, xb.x, xb.y, xb.z, xb.w};
                const float4 pr = predict(W, X);
                if (STORE_PRED) {
                    uint2 u = { packh2(pr.x, pr.y), packh2(pr.z, pr.w) };
                    ntstore2(&pred_out[((size_t)(b0 + j2) * P_SZ + p) * 256 + t], u);
                }
                sacc[j2].x += pr.x * (1.0f / 32.0f);
                sacc[j2].y += pr.y * (1.0f / 32.0f);
                sacc[j2].z += pr.z * (1.0f / 32.0f);
                sacc[j2].w += pr.w * (1.0f / 32.0f);
            }
        } else {
            #pragma unroll
            for (int h = 0; h < 2; ++h) {
                const int par = h;
                float4 pr[4];
                float  ap[4], ee[4], bold[4];
                if (MODE == 2) {
                    #pragma unroll
                    for (int j2 = 0; j2 < 4; ++j2)
                        bold[j2] = b_io[((size_t)(b0 + h * 4 + j2) * P_SZ + p) * N_SZ + n];
                }
                #pragma unroll
                for (int j2 = 0; j2 < 4; ++j2) {
                    const int bl = h * 4 + j2;
                    const uint4* xp = xbase + ((size_t)bl * P_SZ + p) * 2;
                    const uint4 xa = xp[0], xb = xp[1];
                    const unsigned X[8] = {xa.x, xa.y, xa.z, xa.w, xb.x, xb.y, xb.z, xb.w};
                    pr[j2] = predict(W, X);
                    ap[j2] = dot4(pr[j2], unpackh4(vs2[bl * 256 + t]));
                }
                #pragma unroll
                for (int j2 = 0; j2 < 4; ++j2) {
                    ap[j2] += __shfl_xor(ap[j2], 1);
                    ap[j2] += __shfl_xor(ap[j2], 2);
                    ap[j2] += __shfl_xor(ap[j2], 4);
                }
                #pragma unroll
                for (int j2 = 0; j2 < 4; ++j2) {
                    const size_t bidx = ((size_t)(b0 + h * 4 + j2) * P_SZ + p) * N_SZ + n;
                    const float bnew = (MODE == 1) ? ap[j2] : (bold[j2] + ap[j2]);
                    if ((t & 7) == 0) b_io[bidx] = bnew;
                    ee[j2] = __expf(bnew);
                }
                #pragma unroll
                for (int j2 = 0; j2 < 4; ++j2) {
                    float ps = ee[j2];
                    ps += __shfl_xor(ps, 8);
                    ps += __shfl_xor(ps, 16);
                    ps += __shfl_xor(ps, 32);
                    ap[j2] = ps;
                }
                if (lane == 0) {
                    #pragma unroll
                    for (int j2 = 0; j2 < 4; ++j2) sden[par][j2 * 4 + wv] = ap[j2];
                }
                __syncthreads();  // parity-buffered sden: race-free (r2 argument)
                #pragma unroll
                for (int j2 = 0; j2 < 4; ++j2) {
                    const int bl = h * 4 + j2;
                    const float4 dd = *(const float4*)&sden[par][j2 * 4];
                    const float c = ee[j2] * __builtin_amdgcn_rcpf(dd.x + dd.y + dd.z + dd.w);
                    sacc[bl].x += c * pr[j2].x; sacc[bl].y += c * pr[j2].y;
                    sacc[bl].z += c * pr[j2].z; sacc[bl].w += c * pr[j2].w;
                }
            }
        }
    }

    #pragma unroll
    for (int j2 = 0; j2 < BC; ++j2) {
        uint2 u = { packh2(sacc[j2].x, sacc[j2].y), packh2(sacc[j2].z, sacc[j2].w) };
        s_part[((size_t)pc * B_SZ + (b0 + j2)) * 256 + t] = u;
    }
}

// -------- r16 routing: r15 structure, spill-free occupancy bound --------
// r15's __launch_bounds__(256,8) capped VGPR at 32 -> ~150 MB scratch spill
// per pass (WRITE_SIZE 170 MB, dur 102 us). (256,4) gives 128 VGPR: the
// prefetch pipeline (~60 live regs) fits with zero spill.
// One wave owns (b, 16-p chunk). Lane l owns nd [8l,8l+8) and [512+8l,+8).
// XCD-aware decode: xcd = bid&7 owns b range [xcd*8, +8). nt loads: pred is
// a read-once 256 MB stream. Cumulative-v logits: b_k = pred . vsum.
__global__ __launch_bounds__(256, 4) void routing_wave(
    const uint4* __restrict__ pred, const float* __restrict__ vsum,
    uint4* __restrict__ s_part)
{
    const int t    = threadIdx.x;
    const int wv   = t >> 6;
    const int lane = t & 63;
    const int xcd  = blockIdx.x & 7;
    const int jj   = blockIdx.x >> 3;         // 0..255
    const int gl   = jj * 4 + wv;             // 0..1023 within XCD
    const int b    = xcd * 8 + (gl >> 7);     // 0..63
    const int pch  = gl & (NPCH - 1);         // 0..127
    const int p0   = pch * PP;

    // vsum (f32) -> f16 pairs in regs: 8 d-values for (b,n_lo) and (b,n_hi)
    unsigned vlo[4], vhi[4];
    {
        const float4* vp = (const float4*)vsum + ((size_t)b * 256 + 2 * lane);
        const float4 a0 = vp[0],   a1 = vp[1];
        const float4 b0 = vp[128], b1 = vp[129];
        vlo[0] = packh2(a0.x, a0.y); vlo[1] = packh2(a0.z, a0.w);
        vlo[2] = packh2(a1.x, a1.y); vlo[3] = packh2(a1.z, a1.w);
        vhi[0] = packh2(b0.x, b0.y); vhi[1] = packh2(b0.z, b0.w);
        vhi[2] = packh2(b1.x, b1.y); vhi[3] = packh2(b1.z, b1.w);
    }

    float slo[8], shi[8];
    #pragma unroll
    for (int i = 0; i < 8; ++i) { slo[i] = 0.f; shi[i] = 0.f; }

    const uint4* pb = pred + ((size_t)b * P_SZ + p0) * 128 + lane;

    uint4 A  = ntload4(pb);        // nd [8*lane, +8)      contiguous 1 KiB
    uint4 Bq = ntload4(pb + 64);   // nd [512+8*lane, +8)  contiguous 1 KiB

    #pragma unroll
    for (int pl = 0; pl < PP; ++pl) {
        uint4 An, Bn;
        if (pl + 1 < PP) {
            An = ntload4(pb + 128);
            Bn = ntload4(pb + 192);
        }
        float alo = 0.f, ahi = 0.f;
        alo = dot2acc(A.x,  vlo[0], alo); alo = dot2acc(A.y,  vlo[1], alo);
        alo = dot2acc(A.z,  vlo[2], alo); alo = dot2acc(A.w,  vlo[3], alo);
        ahi = dot2acc(Bq.x, vhi[0], ahi); ahi = dot2acc(Bq.y, vhi[1], ahi);
        ahi = dot2acc(Bq.z, vhi[2], ahi); ahi = dot2acc(Bq.w, vhi[3], ahi);
        alo += __shfl_xor(alo, 1);  alo += __shfl_xor(alo, 2);
        ahi += __shfl_xor(ahi, 1);  ahi += __shfl_xor(ahi, 2);
        const float elo = __expf(alo), ehi = __expf(ahi);
        float den = elo + ehi;
        den += __shfl_xor(den, 4);   den += __shfl_xor(den, 8);
        den += __shfl_xor(den, 16);  den += __shfl_xor(den, 32);
        const float r   = __builtin_amdgcn_rcpf(den);
        const float clo = elo * r, chi = ehi * r;
        const unsigned XA[4] = {A.x,  A.y,  A.z,  A.w};
        const unsigned XB[4] = {Bq.x, Bq.y, Bq.z, Bq.w};
        #pragma unroll
        for (int i = 0; i < 4; ++i) {
            const half2_t ha = __builtin_bit_cast(half2_t, XA[i]);
            const half2_t hb = __builtin_bit_cast(half2_t, XB[i]);
            slo[2 * i]     += clo * (float)ha[0];
            slo[2 * i + 1] += clo * (float)ha[1];
            shi[2 * i]     += chi * (float)hb[0];
            shi[2 * i + 1] += chi * (float)hb[1];
        }
        A = An; Bq = Bn;
        pb += 128;
    }

    uint4 o0, o1;
    o0.x = packh2(slo[0], slo[1]); o0.y = packh2(slo[2], slo[3]);
    o0.z = packh2(slo[4], slo[5]); o0.w = packh2(slo[6], slo[7]);
    o1.x = packh2(shi[0], shi[1]); o1.y = packh2(shi[2], shi[3]);
    o1.z = packh2(shi[4], shi[5]); o1.w = packh2(shi[6], shi[7]);
    uint4* sp = s_part + ((size_t)pch * B_SZ + b) * 128;
    sp[lane]      = o0;   // nd [8*lane, +8)      contiguous
    sp[64 + lane] = o1;   // nd [512+8*lane, +8)  contiguous
}

// s[b][nd] = sum over NPCH wave-partials (f16, fp32 accum); v = squash(s).
// VMODE 1: dst += v (vsum accumulate); VMODE 2: dst = v (out)
template <int VMODE>
__global__ __launch_bounds__(256) void reduce_squash2(
    const uint2* __restrict__ s_part, float* __restrict__ dst)
{
    const int t   = threadIdx.x;
    const int b   = blockIdx.x;
    const int q   = blockIdx.y;
    const int l   = t & 63;
    const int sub = t >> 6;
    const int nd4 = q * 64 + l;

    float4 s = make_float4(0.f, 0.f, 0.f, 0.f);
    for (int i = 0; i < NPCH / 4; ++i) {
        const int pcid = sub + 4 * i;
        const float4 v = unpackh4(s_part[((size_t)pcid * B_SZ + b) * 256 + nd4]);
        s.x += v.x; s.y += v.y; s.z += v.z; s.w += v.w;
    }
    __shared__ float4 red[3][64];
    if (sub > 0) red[sub - 1][l] = s;
    __syncthreads();
    if (t < 64) {
        #pragma unroll
        for (int wvi = 0; wvi < 3; ++wvi) {
            const float4 r = red[wvi][t];
            s.x += r.x; s.y += r.y; s.z += r.z; s.w += r.w;
        }
        float sq = dot4(s, s);
        sq += __shfl_xor(sq, 1);
        sq += __shfl_xor(sq, 2);
        sq += __shfl_xor(sq, 4);
        const float f = sq / ((1.0f + sq) * sqrtf(sq + 1e-7f));
        float4 o = make_float4(f * s.x, f * s.y, f * s.z, f * s.w);
        if (VMODE == 1) {
            const float4 old = ((const float4*)dst)[(size_t)b * 256 + nd4];
            o.x += old.x; o.y += old.y; o.z += old.z; o.w += old.w;
        }
        ((float4*)dst)[(size_t)b * 256 + nd4] = o;
    }
}

// old reducer (NPC=256 partials) — consumes pass0's s_part
__global__ __launch_bounds__(256) void reduce_squash(
    const uint2* __restrict__ s_part, float* __restrict__ dst)
{
    const int t  = threadIdx.x;
    const int b  = blockIdx.x;
    const int q  = blockIdx.y;
    const int l  = t & 63;
    const int sub = t >> 6;
    const int nd4 = q * 64 + l;

    float4 s = make_float4(0.f, 0.f, 0.f, 0.f);
    for (int i = 0; i < NPC / 4; ++i) {
        const int pcid = sub + 4 * i;
        const float4 v = unpackh4(s_part[((size_t)pcid * B_SZ + b) * 256 + nd4]);
        s.x += v.x; s.y += v.y; s.z += v.z; s.w += v.w;
    }
    __shared__ float4 red[3][64];
    if (sub > 0) red[sub - 1][l] = s;
    __syncthreads();
    if (t < 64) {
        #pragma unroll
        for (int wvi = 0; wvi < 3; ++wvi) {
            const float4 r = red[wvi][t];
            s.x += r.x; s.y += r.y; s.z += r.z; s.w += r.w;
        }
        float sq = dot4(s, s);
        sq += __shfl_xor(sq, 1);
        sq += __shfl_xor(sq, 2);
        sq += __shfl_xor(sq, 4);
        const float f = sq / ((1.0f + sq) * sqrtf(sq + 1e-7f));
        ((float4*)dst)[(size_t)b * 256 + nd4] =
            make_float4(f * s.x, f * s.y, f * s.z, f * s.w);
    }
}

extern "C" void kernel_launch(void* const* d_in, const int* in_sizes, int n_in,
                              void* d_out, int out_size, void* d_ws, size_t ws_size,
                              hipStream_t stream)
{
    const float* x = (const float*)d_in[0];   // (B,P,pD)
    const float* w = (const float*)d_in[1];   // (P,N,D,pD)
    float* out = (float*)d_out;               // (B,N,D)
    float* ws  = (float*)d_ws;

    // ---- workspace layout (float offsets):
    //   vsum  : [0,        65536)      256 KiB
    //   s_part: [65536,    8454144)    32 MiB pass0 layout; routing's 16 MiB
    //           aliases the front (sequenced: pass0 partials consumed first)
    //   w2    : [8454144,  25231360)   64 MiB
    //   x2    : [25231360, 26279936)    4 MiB
    //   pred  : [26279936, 93388800)  256 MiB
    float*    v_buf  = ws;
    uint2*    s_part = (uint2*)(ws + 65536);
    unsigned* w2     = (unsigned*)(ws + 8454144);
    uint4*    x2     = (uint4*)(ws + 25231360);
    uint2*    pred   = (uint2*)(ws + 26279936);
    float*    b_fb   = ws + 26279936;             // fallback only (pred unused)
    const size_t need = 93388800ull * 4ull;       // 373,555,200 B

    repack_wx<<<dim3(9216), dim3(256), 0, stream>>>((const float4*)w, (uint4*)w2,
                                                    (const float4*)x, (uint4*)x2);

    dim3 fg(NPC * NBC), fb(256);   // r12: 1D grid, XCD-sliced decode in-kernel
    dim3 rg(B_SZ, 4), rb(256);

    if (ws_size >= need) {
        // pass0 computes pred once + stores f16 (nt); routing passes stream
        // pred (nt loads) with cumulative-v logits.
        fused_pass<0, true><<<fg, fb, 0, stream>>>(x2, (const uint4*)w2, nullptr,
                                                   nullptr, s_part, pred);
        reduce_squash<<<rg, rb, 0, stream>>>(s_part, v_buf);          // vsum = v1

        routing_wave<<<dim3(2048), dim3(256), 0, stream>>>(
            (const uint4*)pred, v_buf, (uint4*)s_part);
        reduce_squash2<1><<<rg, rb, 0, stream>>>(s_part, v_buf);      // vsum += v2

        routing_wave<<<dim3(2048), dim3(256), 0, stream>>>(
            (const uint4*)pred, v_buf, (uint4*)s_part);
        reduce_squash2<1><<<rg, rb, 0, stream>>>(s_part, v_buf);      // vsum += v3

        routing_wave<<<dim3(2048), dim3(256), 0, stream>>>(
            (const uint4*)pred, v_buf, (uint4*)s_part);
        reduce_squash2<2><<<rg, rb, 0, stream>>>(s_part, out);        // final v
    } else {
        // r7 fallback (recompute pred every pass)
        fused_pass<0, false><<<fg, fb, 0, stream>>>(x2, (const uint4*)w2, nullptr,
                                                    nullptr, s_part, nullptr);
        reduce_squash<<<rg, rb, 0, stream>>>(s_part, v_buf);
        fused_pass<1, false><<<fg, fb, 0, stream>>>(x2, (const uint4*)w2, v_buf,
                                                    b_fb, s_part, nullptr);
        reduce_squash<<<rg, rb, 0, stream>>>(s_part, v_buf);
        fused_pass<2, false><<<fg, fb, 0, stream>>>(x2, (const uint4*)w2, v_buf,
                                                    b_fb, s_part, nullptr);
        reduce_squash<<<rg, rb, 0, stream>>>(s_part, v_buf);
        fused_pass<2, false><<<fg, fb, 0, stream>>>(x2, (const uint4*)w2, v_buf,
                                                    b_fb, s_part, nullptr);
        reduce_squash<<<rg, rb, 0, stream>>>(s_part, out);
    }
}

// Round 10
// 429.763 us; speedup vs baseline: 1.3264x; 1.0032x over previous
//
#include <hip/hip_runtime.h>
#include <math.h>

// DigitCaps routing constants
#define B_SZ 64
#define P_SZ 2048
#define PD   16
#define N_SZ 32
#define D_SZ 32
#define ND   1024            // N_SZ * D_SZ
#define PC   8               // p per fused block (pass0)
#define BC   8               // b per fused block (pass0)
#define NPC  (P_SZ / PC)     // 256
#define NBC  (B_SZ / BC)     // 8
#define PP   16              // p per wave in routing_wave
#define NPCH (P_SZ / PP)     // 128 partials

typedef _Float16 half2_t __attribute__((ext_vector_type(2)));
typedef unsigned u32x2 __attribute__((ext_vector_type(2)));

__device__ __forceinline__ float dot2acc(unsigned a, unsigned b, float acc) {
#if __has_builtin(__builtin_amdgcn_fdot2)
    return __builtin_amdgcn_fdot2(__builtin_bit_cast(half2_t, a),
                                  __builtin_bit_cast(half2_t, b), acc, false);
#else
    const half2_t ha = __builtin_bit_cast(half2_t, a);
    const half2_t hb = __builtin_bit_cast(half2_t, b);
    return acc + (float)ha[0] * (float)hb[0] + (float)ha[1] * (float)hb[1];
#endif
}

__device__ __forceinline__ unsigned packh2(float a, float b) {
    half2_t h; h[0] = (_Float16)a; h[1] = (_Float16)b;
    return __builtin_bit_cast(unsigned, h);
}

__device__ __forceinline__ float4 unpackh4(uint2 u) {
    const half2_t lo = __builtin_bit_cast(half2_t, u.x);
    const half2_t hi = __builtin_bit_cast(half2_t, u.y);
    return make_float4((float)lo[0], (float)lo[1], (float)hi[0], (float)hi[1]);
}

__device__ __forceinline__ float dot4(const float4 a, const float4 b) {
    return a.x * b.x + a.y * b.y + a.z * b.z + a.w * b.w;
}

__device__ __forceinline__ void ntstore2(uint2* p, uint2 x) {
    u32x2 v; v[0] = x.x; v[1] = x.y;
    __builtin_nontemporal_store(v, (u32x2*)p);
}

// r14 merged repack: blocks [0,8192) repack W, [8192,9216) repack x.
// W part (r12 mapping): reads 64 B dense/thread, writes 2 coalesced uint4.
// w2u4[(p*8+k)*256 + t] holds w[p][4t + (k>>1)][(k&1)*8 .. +7] as f16.
__global__ __launch_bounds__(256) void repack_wx(
    const float4* __restrict__ w4, uint4* __restrict__ w2u4,
    const float4* __restrict__ x4, uint4* __restrict__ x2)
{
    const int blk = blockIdx.x;
    if (blk < 8192) {
        const size_t g = (size_t)blk * 256 + threadIdx.x;  // < 2097152
        const int p    = (int)(g >> 10);
        const int q    = (int)((g >> 8) & 3);
        const int t    = (int)(g & 255);
        const size_t f0 = ((size_t)p * 1024 + 4 * t + q) * 4;
        const float4 a = w4[f0], b = w4[f0 + 1], c = w4[f0 + 2], d = w4[f0 + 3];
        uint4 o0, o1;
        o0.x = packh2(a.x, a.y); o0.y = packh2(a.z, a.w);
        o0.z = packh2(b.x, b.y); o0.w = packh2(b.z, b.w);
        o1.x = packh2(c.x, c.y); o1.y = packh2(c.z, c.w);
        o1.z = packh2(d.x, d.y); o1.w = packh2(d.z, d.w);
        w2u4[((size_t)p * 8 + 2 * q) * 256 + t]     = o0;
        w2u4[((size_t)p * 8 + 2 * q + 1) * 256 + t] = o1;
    } else {
        const size_t g = (size_t)(blk - 8192) * 256 + threadIdx.x;  // < 262144
        const float4 a = x4[g * 2], b = x4[g * 2 + 1];
        uint4 o;
        o.x = packh2(a.x, a.y); o.y = packh2(a.z, a.w);
        o.z = packh2(b.x, b.y); o.w = packh2(b.z, b.w);
        x2[g] = o;
    }
}

__device__ __forceinline__ float4 predict(const uint4 (&W)[8], const unsigned* X) {
    float s; float4 pr;
    s = dot2acc(W[0].x, X[0], 0.f); s = dot2acc(W[0].y, X[1], s);
    s = dot2acc(W[0].z, X[2], s);   s = dot2acc(W[0].w, X[3], s);
    s = dot2acc(W[1].x, X[4], s);   s = dot2acc(W[1].y, X[5], s);
    s = dot2acc(W[1].z, X[6], s);   s = dot2acc(W[1].w, X[7], s);
    pr.x = s;
    s = dot2acc(W[2].x, X[0], 0.f); s = dot2acc(W[2].y, X[1], s);
    s = dot2acc(W[2].z, X[2], s);   s = dot2acc(W[2].w, X[3], s);
    s = dot2acc(W[3].x, X[4], s);   s = dot2acc(W[3].y, X[5], s);
    s = dot2acc(W[3].z, X[6], s);   s = dot2acc(W[3].w, X[7], s);
    pr.y = s;
    s = dot2acc(W[4].x, X[0], 0.f); s = dot2acc(W[4].y, X[1], s);
    s = dot2acc(W[4].z, X[2], s);   s = dot2acc(W[4].w, X[3], s);
    s = dot2acc(W[5].x, X[4], s);   s = dot2acc(W[5].y, X[5], s);
    s = dot2acc(W[5].z, X[6], s);   s = dot2acc(W[5].w, X[7], s);
    pr.z = s;
    s = dot2acc(W[6].x, X[0], 0.f); s = dot2acc(W[6].y, X[1], s);
    s = dot2acc(W[6].z, X[2], s);   s = dot2acc(W[6].w, X[3], s);
    s = dot2acc(W[7].x, X[4], s);   s = dot2acc(W[7].y, X[5], s);
    s = dot2acc(W[7].z, X[6], s);   s = dot2acc(W[7].w, X[7], s);
    pr.w = s;
    return pr;
}

// r12 fused kernel: 1D grid of 2048 blocks, XCD-sliced W ownership (verified
// r12: FETCH 266 -> 37 MB). r15: pred stores non-temporal (pass0 105 -> <80).
// Thread t owns nd = 4t..4t+3 (n = t>>3).
// MODE==0: c=1/32; MODE==1: b=agr; MODE==2: b+=agr; c=softmax_n(b)
template <int MODE, bool STORE_PRED>
__global__ __launch_bounds__(256, 4) void fused_pass(
    const uint4* __restrict__ x2, const uint4* __restrict__ w2,
    const float* __restrict__ v_in, float* __restrict__ b_io,
    uint2* __restrict__ s_part, uint2* __restrict__ pred_out)
{
    const int t     = threadIdx.x;
    const int gblk  = blockIdx.x;          // 0..2047
    const int xcd   = gblk & 7;
    const int j     = gblk >> 3;           // 0..255
    const int pc    = xcd * (NPC / 8) + (j >> 3);
    const int bc    = j & 7;
    const int p0    = pc * PC, b0 = bc * BC;
    const int n     = t >> 3;
    const int wv    = t >> 6;
    const int lane  = t & 63;

    __shared__ uint2 vs2[BC * 256];        // v as f16 pairs, 16 KiB
    __shared__ float sden[2][16];

    if (MODE != 0) {
        const float4* vg = (const float4*)v_in;
        #pragma unroll
        for (int i = 0; i < BC; ++i) {
            const int idx = t + 256 * i;
            const float4 vv = vg[(size_t)(b0 + (idx >> 8)) * 256 + (idx & 255)];
            uint2 u = { packh2(vv.x, vv.y), packh2(vv.z, vv.w) };
            vs2[idx] = u;
        }
        __syncthreads();
    }

    float4 sacc[BC];
    #pragma unroll
    for (int i = 0; i < BC; ++i) sacc[i] = make_float4(0.f, 0.f, 0.f, 0.f);

    const uint4* wbase = w2 + (size_t)p0 * (8 * 256) + t;
    const uint4* xbase = x2 + (size_t)b0 * P_SZ * 2;

    for (int pl = 0; pl < PC; ++pl) {
        const int p = p0 + pl;
        uint4 W[8];
        #pragma unroll
        for (int k = 0; k < 8; ++k) W[k] = wbase[(size_t)pl * 2048 + k * 256];

        if (MODE == 0) {
            #pragma unroll
            for (int j2 = 0; j2 < BC; ++j2) {
                const uint4* xp = xbase + ((size_t)j2 * P_SZ + p) * 2;
                const uint4 xa = xp[0], xb = xp[1];
                const unsigned X[8] = {xa.x, xa.y, xa.z, xa.w, xb.x, xb.y, xb.z, xb.w};
                const float4 pr = predict(W, X);
                if (STORE_PRED) {
                    uint2 u = { packh2(pr.x, pr.y), packh2(pr.z, pr.w) };
                    ntstore2(&pred_out[((size_t)(b0 + j2) * P_SZ + p) * 256 + t], u);
                }
                sacc[j2].x += pr.x * (1.0f / 32.0f);
                sacc[j2].y += pr.y * (1.0f / 32.0f);
                sacc[j2].z += pr.z * (1.0f / 32.0f);
                sacc[j2].w += pr.w * (1.0f / 32.0f);
            }
        } else {
            #pragma unroll
            for (int h = 0; h < 2; ++h) {
                const int par = h;
                float4 pr[4];
                float  ap[4], ee[4], bold[4];
                if (MODE == 2) {
                    #pragma unroll
                    for (int j2 = 0; j2 < 4; ++j2)
                        bold[j2] = b_io[((size_t)(b0 + h * 4 + j2) * P_SZ + p) * N_SZ + n];
                }
                #pragma unroll
                for (int j2 = 0; j2 < 4; ++j2) {
                    const int bl = h * 4 + j2;
                    const uint4* xp = xbase + ((size_t)bl * P_SZ + p) * 2;
                    const uint4 xa = xp[0], xb = xp[1];
                    const unsigned X[8] = {xa.x, xa.y, xa.z, xa.w, xb.x, xb.y, xb.z, xb.w};
                    pr[j2] = predict(W, X);
                    ap[j2] = dot4(pr[j2], unpackh4(vs2[bl * 256 + t]));
                }
                #pragma unroll
                for (int j2 = 0; j2 < 4; ++j2) {
                    ap[j2] += __shfl_xor(ap[j2], 1);
                    ap[j2] += __shfl_xor(ap[j2], 2);
                    ap[j2] += __shfl_xor(ap[j2], 4);
                }
                #pragma unroll
                for (int j2 = 0; j2 < 4; ++j2) {
                    const size_t bidx = ((size_t)(b0 + h * 4 + j2) * P_SZ + p) * N_SZ + n;
                    const float bnew = (MODE == 1) ? ap[j2] : (bold[j2] + ap[j2]);
                    if ((t & 7) == 0) b_io[bidx] = bnew;
                    ee[j2] = __expf(bnew);
                }
                #pragma unroll
                for (int j2 = 0; j2 < 4; ++j2) {
                    float ps = ee[j2];
                    ps += __shfl_xor(ps, 8);
                    ps += __shfl_xor(ps, 16);
                    ps += __shfl_xor(ps, 32);
                    ap[j2] = ps;
                }
                if (lane == 0) {
                    #pragma unroll
                    for (int j2 = 0; j2 < 4; ++j2) sden[par][j2 * 4 + wv] = ap[j2];
                }
                __syncthreads();  // parity-buffered sden: race-free (r2 argument)
                #pragma unroll
                for (int j2 = 0; j2 < 4; ++j2) {
                    const int bl = h * 4 + j2;
                    const float4 dd = *(const float4*)&sden[par][j2 * 4];
                    const float c = ee[j2] * __builtin_amdgcn_rcpf(dd.x + dd.y + dd.z + dd.w);
                    sacc[bl].x += c * pr[j2].x; sacc[bl].y += c * pr[j2].y;
                    sacc[bl].z += c * pr[j2].z; sacc[bl].w += c * pr[j2].w;
                }
            }
        }
    }

    #pragma unroll
    for (int j2 = 0; j2 < BC; ++j2) {
        uint2 u = { packh2(sacc[j2].x, sacc[j2].y), packh2(sacc[j2].z, sacc[j2].w) };
        s_part[((size_t)pc * B_SZ + (b0 + j2)) * 256 + t] = u;
    }
}

// -------- r17 routing: plain (cache-allocating) loads + zigzag order --------
// r16 used nt loads: evict-first marking prevents the 256 MB L3 from
// retaining pred between passes -> every pass paid ~206 MB HBM fetch.
// r17: plain loads (pred allocates in L3) and template<REV> reverses the
// wave->(b,pch) enumeration, so pass k+1's FIRST reads are pass k's LAST
// reads (reverse-re-read LRU trick). Launch order: fwd, rev, fwd.
// One wave owns (b, 16-p chunk). Lane l owns nd [8l,8l+8) and [512+8l,+8).
// XCD-aware decode: xcd owns b range [xcd*8, +8). 1-deep prefetch pipeline.
// Cumulative-v logits: b_k = pred . vsum.  (256,4): spill-free (r16 lesson).
template <bool REV>
__global__ __launch_bounds__(256, 4) void routing_wave(
    const uint4* __restrict__ pred, const float* __restrict__ vsum,
    uint4* __restrict__ s_part)
{
    const int t    = threadIdx.x;
    const int wv0  = t >> 6;
    const int lane = t & 63;
    const int bid  = REV ? (2047 - blockIdx.x) : blockIdx.x;
    const int wv   = REV ? (3 - wv0) : wv0;
    const int xcd  = bid & 7;
    const int jj   = bid >> 3;                // 0..255
    const int gl   = jj * 4 + wv;             // 0..1023 within XCD
    const int b    = xcd * 8 + (gl >> 7);     // 0..63
    const int pch  = gl & (NPCH - 1);         // 0..127
    const int p0   = pch * PP;

    // vsum (f32) -> f16 pairs in regs: 8 d-values for (b,n_lo) and (b,n_hi)
    unsigned vlo[4], vhi[4];
    {
        const float4* vp = (const float4*)vsum + ((size_t)b * 256 + 2 * lane);
        const float4 a0 = vp[0],   a1 = vp[1];
        const float4 b0 = vp[128], b1 = vp[129];
        vlo[0] = packh2(a0.x, a0.y); vlo[1] = packh2(a0.z, a0.w);
        vlo[2] = packh2(a1.x, a1.y); vlo[3] = packh2(a1.z, a1.w);
        vhi[0] = packh2(b0.x, b0.y); vhi[1] = packh2(b0.z, b0.w);
        vhi[2] = packh2(b1.x, b1.y); vhi[3] = packh2(b1.z, b1.w);
    }

    float slo[8], shi[8];
    #pragma unroll
    for (int i = 0; i < 8; ++i) { slo[i] = 0.f; shi[i] = 0.f; }

    const uint4* pb = pred + ((size_t)b * P_SZ + p0) * 128 + lane;

    uint4 A  = pb[0];     // nd [8*lane, +8)      contiguous 1 KiB
    uint4 Bq = pb[64];    // nd [512+8*lane, +8)  contiguous 1 KiB

    #pragma unroll
    for (int pl = 0; pl < PP; ++pl) {
        uint4 An, Bn;
        if (pl + 1 < PP) {
            An = pb[128];
            Bn = pb[192];
        }
        float alo = 0.f, ahi = 0.f;
        alo = dot2acc(A.x,  vlo[0], alo); alo = dot2acc(A.y,  vlo[1], alo);
        alo = dot2acc(A.z,  vlo[2], alo); alo = dot2acc(A.w,  vlo[3], alo);
        ahi = dot2acc(Bq.x, vhi[0], ahi); ahi = dot2acc(Bq.y, vhi[1], ahi);
        ahi = dot2acc(Bq.z, vhi[2], ahi); ahi = dot2acc(Bq.w, vhi[3], ahi);
        alo += __shfl_xor(alo, 1);  alo += __shfl_xor(alo, 2);
        ahi += __shfl_xor(ahi, 1);  ahi += __shfl_xor(ahi, 2);
        const float elo = __expf(alo), ehi = __expf(ahi);
        float den = elo + ehi;
        den += __shfl_xor(den, 4);   den += __shfl_xor(den, 8);
        den += __shfl_xor(den, 16);  den += __shfl_xor(den, 32);
        const float r   = __builtin_amdgcn_rcpf(den);
        const float clo = elo * r, chi = ehi * r;
        const unsigned XA[4] = {A.x,  A.y,  A.z,  A.w};
        const unsigned XB[4] = {Bq.x, Bq.y, Bq.z, Bq.w};
        #pragma unroll
        for (int i = 0; i < 4; ++i) {
            const half2_t ha = __builtin_bit_cast(half2_t, XA[i]);
            const half2_t hb = __builtin_bit_cast(half2_t, XB[i]);
            slo[2 * i]     += clo * (float)ha[0];
            slo[2 * i + 1] += clo * (float)ha[1];
            shi[2 * i]     += chi * (float)hb[0];
            shi[2 * i + 1] += chi * (float)hb[1];
        }
        A = An; Bq = Bn;
        pb += 128;
    }

    uint4 o0, o1;
    o0.x = packh2(slo[0], slo[1]); o0.y = packh2(slo[2], slo[3]);
    o0.z = packh2(slo[4], slo[5]); o0.w = packh2(slo[6], slo[7]);
    o1.x = packh2(shi[0], shi[1]); o1.y = packh2(shi[2], shi[3]);
    o1.z = packh2(shi[4], shi[5]); o1.w = packh2(shi[6], shi[7]);
    uint4* sp = s_part + ((size_t)pch * B_SZ + b) * 128;
    sp[lane]      = o0;   // nd [8*lane, +8)      contiguous
    sp[64 + lane] = o1;   // nd [512+8*lane, +8)  contiguous
}

// s[b][nd] = sum over NPCH wave-partials (f16, fp32 accum); v = squash(s).
// VMODE 1: dst += v (vsum accumulate); VMODE 2: dst = v (out)
template <int VMODE>
__global__ __launch_bounds__(256) void reduce_squash2(
    const uint2* __restrict__ s_part, float* __restrict__ dst)
{
    const int t   = threadIdx.x;
    const int b   = blockIdx.x;
    const int q   = blockIdx.y;
    const int l   = t & 63;
    const int sub = t >> 6;
    const int nd4 = q * 64 + l;

    float4 s = make_float4(0.f, 0.f, 0.f, 0.f);
    for (int i = 0; i < NPCH / 4; ++i) {
        const int pcid = sub + 4 * i;
        const float4 v = unpackh4(s_part[((size_t)pcid * B_SZ + b) * 256 + nd4]);
        s.x += v.x; s.y += v.y; s.z += v.z; s.w += v.w;
    }
    __shared__ float4 red[3][64];
    if (sub > 0) red[sub - 1][l] = s;
    __syncthreads();
    if (t < 64) {
        #pragma unroll
        for (int wvi = 0; wvi < 3; ++wvi) {
            const float4 r = red[wvi][t];
            s.x += r.x; s.y += r.y; s.z += r.z; s.w += r.w;
        }
        float sq = dot4(s, s);
        sq += __shfl_xor(sq, 1);
        sq += __shfl_xor(sq, 2);
        sq += __shfl_xor(sq, 4);
        const float f = sq / ((1.0f + sq) * sqrtf(sq + 1e-7f));
        float4 o = make_float4(f * s.x, f * s.y, f * s.z, f * s.w);
        if (VMODE == 1) {
            const float4 old = ((const float4*)dst)[(size_t)b * 256 + nd4];
            o.x += old.x; o.y += old.y; o.z += old.z; o.w += old.w;
        }
        ((float4*)dst)[(size_t)b * 256 + nd4] = o;
    }
}

// old reducer (NPC=256 partials) — consumes pass0's s_part
__global__ __launch_bounds__(256) void reduce_squash(
    const uint2* __restrict__ s_part, float* __restrict__ dst)
{
    const int t  = threadIdx.x;
    const int b  = blockIdx.x;
    const int q  = blockIdx.y;
    const int l  = t & 63;
    const int sub = t >> 6;
    const int nd4 = q * 64 + l;

    float4 s = make_float4(0.f, 0.f, 0.f, 0.f);
    for (int i = 0; i < NPC / 4; ++i) {
        const int pcid = sub + 4 * i;
        const float4 v = unpackh4(s_part[((size_t)pcid * B_SZ + b) * 256 + nd4]);
        s.x += v.x; s.y += v.y; s.z += v.z; s.w += v.w;
    }
    __shared__ float4 red[3][64];
    if (sub > 0) red[sub - 1][l] = s;
    __syncthreads();
    if (t < 64) {
        #pragma unroll
        for (int wvi = 0; wvi < 3; ++wvi) {
            const float4 r = red[wvi][t];
            s.x += r.x; s.y += r.y; s.z += r.z; s.w += r.w;
        }
        float sq = dot4(s, s);
        sq += __shfl_xor(sq, 1);
        sq += __shfl_xor(sq, 2);
        sq += __shfl_xor(sq, 4);
        const float f = sq / ((1.0f + sq) * sqrtf(sq + 1e-7f));
        ((float4*)dst)[(size_t)b * 256 + nd4] =
            make_float4(f * s.x, f * s.y, f * s.z, f * s.w);
    }
}

extern "C" void kernel_launch(void* const* d_in, const int* in_sizes, int n_in,
                              void* d_out, int out_size, void* d_ws, size_t ws_size,
                              hipStream_t stream)
{
    const float* x = (const float*)d_in[0];   // (B,P,pD)
    const float* w = (const float*)d_in[1];   // (P,N,D,pD)
    float* out = (float*)d_out;               // (B,N,D)
    float* ws  = (float*)d_ws;

    // ---- workspace layout (float offsets):
    //   vsum  : [0,        65536)      256 KiB
    //   s_part: [65536,    8454144)    32 MiB pass0 layout; routing's 16 MiB
    //           aliases the front (sequenced: pass0 partials consumed first)
    //   w2    : [8454144,  25231360)   64 MiB
    //   x2    : [25231360, 26279936)    4 MiB
    //   pred  : [26279936, 93388800)  256 MiB
    float*    v_buf  = ws;
    uint2*    s_part = (uint2*)(ws + 65536);
    unsigned* w2     = (unsigned*)(ws + 8454144);
    uint4*    x2     = (uint4*)(ws + 25231360);
    uint2*    pred   = (uint2*)(ws + 26279936);
    float*    b_fb   = ws + 26279936;             // fallback only (pred unused)
    const size_t need = 93388800ull * 4ull;       // 373,555,200 B

    repack_wx<<<dim3(9216), dim3(256), 0, stream>>>((const float4*)w, (uint4*)w2,
                                                    (const float4*)x, (uint4*)x2);

    dim3 fg(NPC * NBC), fb(256);   // r12: 1D grid, XCD-sliced decode in-kernel
    dim3 rg(B_SZ, 4), rb(256);

    if (ws_size >= need) {
        // pass0 computes pred once + stores f16 (nt); routing passes stream
        // pred with zigzag order for cross-pass L3 reuse.
        fused_pass<0, true><<<fg, fb, 0, stream>>>(x2, (const uint4*)w2, nullptr,
                                                   nullptr, s_part, pred);
        reduce_squash<<<rg, rb, 0, stream>>>(s_part, v_buf);          // vsum = v1

        routing_wave<false><<<dim3(2048), dim3(256), 0, stream>>>(
            (const uint4*)pred, v_buf, (uint4*)s_part);
        reduce_squash2<1><<<rg, rb, 0, stream>>>(s_part, v_buf);      // vsum += v2

        routing_wave<true><<<dim3(2048), dim3(256), 0, stream>>>(
            (const uint4*)pred, v_buf, (uint4*)s_part);
        reduce_squash2<1><<<rg, rb, 0, stream>>>(s_part, v_buf);      // vsum += v3

        routing_wave<false><<<dim3(2048), dim3(256), 0, stream>>>(
            (const uint4*)pred, v_buf, (uint4*)s_part);
        reduce_squash2<2><<<rg, rb, 0, stream>>>(s_part, out);        // final v
    } else {
        // r7 fallback (recompute pred every pass)
        fused_pass<0, false><<<fg, fb, 0, stream>>>(x2, (const uint4*)w2, nullptr,
                                                    nullptr, s_part, nullptr);
        reduce_squash<<<rg, rb, 0, stream>>>(s_part, v_buf);
        fused_pass<1, false><<<fg, fb, 0, stream>>>(x2, (const uint4*)w2, v_buf,
                                                    b_fb, s_part, nullptr);
        reduce_squash<<<rg, rb, 0, stream>>>(s_part, v_buf);
        fused_pass<2, false><<<fg, fb, 0, stream>>>(x2, (const uint4*)w2, v_buf,
                                                    b_fb, s_part, nullptr);
        reduce_squash<<<rg, rb, 0, stream>>>(s_part, v_buf);
        fused_pass<2, false><<<fg, fb, 0, stream>>>(x2, (const uint4*)w2, v_buf,
                                                    b_fb, s_part, nullptr);
        reduce_squash<<<rg, rb, 0, stream>>>(s_part, out);
    }
}